// Round 2
// baseline (16636.890 us; speedup 1.0000x reference)
//
#include <hip/hip_runtime.h>
#include <stdint.h>

// Problem dims
#define BB 32
#define SS 128
#define TT 96
#define HH 1024
#define VV 32000

typedef short bf16x8 __attribute__((ext_vector_type(8)));
typedef float f32x4 __attribute__((ext_vector_type(4)));

__device__ inline unsigned short f2bf(float f) {
    union { float f; unsigned int i; } x; x.f = f;
    unsigned int r = x.i + 0x7fffu + ((x.i >> 16) & 1u);
    return (unsigned short)(r >> 16);
}
__device__ inline float sigmoidf_(float x) {
    float xc = fminf(fmaxf(x, -30.0f), 30.0f);
    return 1.0f / (1.0f + __expf(-xc));
}
__device__ inline float tanhf_(float x) {
    float x2 = fminf(fmaxf(2.0f * x, -30.0f), 30.0f);
    float e = __expf(x2);
    return (e - 1.0f) / (e + 1.0f);
}

// ---------------------------------------------------------------------------
// 128x128-tile GEMM: C[M,N] = A[M,K] @ B[K,N] + bias   (fp32 in/out,
// bf16 MFMA internally; A/B converted to bf16 during LDS staging)
// A rows optionally gathered: row -> gbase + gidx[row]*lda
// Requires N%128==0, K%32==0; M arbitrary (clamped loads, guarded stores)
// ---------------------------------------------------------------------------
template<bool GATHER>
__global__ __launch_bounds__(256)
void gemm128(const float* __restrict__ A, long lda,
             const int* __restrict__ gidx, const float* __restrict__ gbase,
             const float* __restrict__ Bkn, long ldb,
             const float* __restrict__ bias,
             float* __restrict__ Cout, long ldc,
             int M, int N, int K)
{
    __shared__ __align__(16) unsigned short At[128 * 32];
    __shared__ __align__(16) unsigned short Bt[128 * 32];
    const int tid = threadIdx.x;
    const int m0 = blockIdx.y * 128, n0 = blockIdx.x * 128;
    const int lane = tid & 63, wave = tid >> 6;
    const int wr = wave >> 1, wc = wave & 1;
    const int lm = lane & 15, quad = lane >> 4;

    f32x4 acc[4][4] = {};

    for (int kt = 0; kt < K; kt += 32) {
        // Stage A: fp32 -> bf16, At[row][k] row-major
#pragma unroll
        for (int i = 0; i < 2; ++i) {
            int c = i * 256 + tid;
            int row = c >> 2, col = (c & 3) << 3;
            int rg = m0 + row; if (rg > M - 1) rg = M - 1;
            const float* src;
            if (GATHER) src = gbase + (size_t)gidx[rg] * lda + kt + col;
            else        src = A + (size_t)rg * lda + kt + col;
            float4 f0 = *(const float4*)src;
            float4 f1 = *(const float4*)(src + 4);
            union { int4 v; unsigned short u[8]; } t;
            t.u[0] = f2bf(f0.x); t.u[1] = f2bf(f0.y); t.u[2] = f2bf(f0.z); t.u[3] = f2bf(f0.w);
            t.u[4] = f2bf(f1.x); t.u[5] = f2bf(f1.y); t.u[6] = f2bf(f1.z); t.u[7] = f2bf(f1.w);
            *(int4*)(At + row * 32 + col) = t.v;
        }
        // Stage B: fp32 [k][n] -> bf16 transposed Bt[n][k]
#pragma unroll
        for (int i = 0; i < 2; ++i) {
            int c = i * 256 + tid;
            int kr = c >> 4, nc = (c & 15) << 3;
            const float* src = Bkn + (size_t)(kt + kr) * ldb + n0 + nc;
            float4 f0 = *(const float4*)src;
            float4 f1 = *(const float4*)(src + 4);
            Bt[(nc + 0) * 32 + kr] = f2bf(f0.x);
            Bt[(nc + 1) * 32 + kr] = f2bf(f0.y);
            Bt[(nc + 2) * 32 + kr] = f2bf(f0.z);
            Bt[(nc + 3) * 32 + kr] = f2bf(f0.w);
            Bt[(nc + 4) * 32 + kr] = f2bf(f1.x);
            Bt[(nc + 5) * 32 + kr] = f2bf(f1.y);
            Bt[(nc + 6) * 32 + kr] = f2bf(f1.z);
            Bt[(nc + 7) * 32 + kr] = f2bf(f1.w);
        }
        __syncthreads();

        bf16x8 af[4], bfr[4];
#pragma unroll
        for (int i = 0; i < 4; ++i)
            af[i] = *(const bf16x8*)(At + (wr * 64 + i * 16 + lm) * 32 + quad * 8);
#pragma unroll
        for (int j = 0; j < 4; ++j)
            bfr[j] = *(const bf16x8*)(Bt + (wc * 64 + j * 16 + lm) * 32 + quad * 8);
#pragma unroll
        for (int i = 0; i < 4; ++i)
#pragma unroll
            for (int j = 0; j < 4; ++j)
                acc[i][j] = __builtin_amdgcn_mfma_f32_16x16x32_bf16(af[i], bfr[j], acc[i][j], 0, 0, 0);
        __syncthreads();
    }

    // Epilogue: C/D layout col=lane&15, row=quad*4+reg  [m89-verified]
#pragma unroll
    for (int i = 0; i < 4; ++i) {
        int r0 = m0 + wr * 64 + i * 16 + quad * 4;
#pragma unroll
        for (int j = 0; j < 4; ++j) {
            int col = n0 + wc * 64 + j * 16 + lm;
            float bb = bias ? bias[col] : 0.0f;
#pragma unroll
            for (int r = 0; r < 4; ++r) {
                int row = r0 + r;
                if (row < M)
                    Cout[(size_t)row * ldc + col] = acc[i][j][r] + bb;
            }
        }
    }
}

// ---------------------------------------------------------------------------
// fp32 transpose: src[R][C] -> dst[C][R], R%64==0, C%64==0
// ---------------------------------------------------------------------------
__global__ __launch_bounds__(256)
void transpose_f32(const float* __restrict__ src, float* __restrict__ dst,
                   int R, int C)
{
    __shared__ __align__(16) float tile[64 * 68];
    const int r0 = blockIdx.y * 64, c0 = blockIdx.x * 64;
    const int tid = threadIdx.x;
#pragma unroll
    for (int i = 0; i < 4; ++i) {
        int c = i * 256 + tid;
        int row = c >> 4, col = (c & 15) << 2;
        float4 v = *(const float4*)(src + (size_t)(r0 + row) * C + c0 + col);
        *(float4*)(tile + row * 68 + col) = v;
    }
    __syncthreads();
#pragma unroll
    for (int i = 0; i < 4; ++i) {
        int c = i * 256 + tid;
        int orow = c >> 4, ocol = (c & 15) << 2;
        float4 t4;
        t4.x = tile[(ocol + 0) * 68 + orow];
        t4.y = tile[(ocol + 1) * 68 + orow];
        t4.z = tile[(ocol + 2) * 68 + orow];
        t4.w = tile[(ocol + 3) * 68 + orow];
        *(float4*)(dst + (size_t)(c0 + orow) * R + r0 + ocol) = t4;
    }
}

// ---------------------------------------------------------------------------
// GRU step: h_next = GRU(h_cur, GI[:,t,:]); writes h into combined[:,t,0:H]
// grid 256 (b=wg>>3, jc=wg&7), 256 thr (jl=tid&127, kh=tid>>7). All fp32.
// ---------------------------------------------------------------------------
__global__ __launch_bounds__(256)
void gru_step(const float* __restrict__ hcur, float* __restrict__ hnext,
              const float* __restrict__ GI, const float* __restrict__ WhhT,
              const float* __restrict__ bhh, float* __restrict__ combined,
              int t)
{
    __shared__ float hl[1024];
    __shared__ float red[3 * 256];
    const int b = blockIdx.x >> 3, jc = blockIdx.x & 7;
    const int tid = threadIdx.x, jl = tid & 127, kh = tid >> 7;
    const int j = jc * 128 + jl;
    for (int i = tid; i < 1024; i += 256) hl[i] = hcur[b * 1024 + i];
    __syncthreads();

    const float* w0 = WhhT + (size_t)j * 1024 + kh * 512;
    const float* w1 = WhhT + (size_t)(1024 + j) * 1024 + kh * 512;
    const float* w2 = WhhT + (size_t)(2048 + j) * 1024 + kh * 512;
    const float* hk = hl + kh * 512;
    float a0 = 0, a1 = 0, a2 = 0;
    for (int c = 0; c < 512; c += 4) {
        float4 t0 = *(const float4*)(w0 + c);
        float4 t1 = *(const float4*)(w1 + c);
        float4 t2 = *(const float4*)(w2 + c);
        float h0 = hk[c], h1 = hk[c + 1], h2 = hk[c + 2], h3 = hk[c + 3];
        a0 += t0.x * h0 + t0.y * h1 + t0.z * h2 + t0.w * h3;
        a1 += t1.x * h0 + t1.y * h1 + t1.z * h2 + t1.w * h3;
        a2 += t2.x * h0 + t2.y * h1 + t2.z * h2 + t2.w * h3;
    }
    red[tid] = a0; red[256 + tid] = a1; red[512 + tid] = a2;
    __syncthreads();
    if (kh == 0) {
        float hr = red[jl] + red[jl + 128];
        float hz = red[256 + jl] + red[256 + jl + 128];
        float hn = red[512 + jl] + red[512 + jl + 128];
        size_t gir = ((size_t)b * TT + t) * 3072;
        float ir = GI[gir + j], iz = GI[gir + 1024 + j], inn = GI[gir + 2048 + j];
        hr += bhh[j]; hz += bhh[1024 + j]; hn += bhh[2048 + j];
        float r = sigmoidf_(ir + hr);
        float z = sigmoidf_(iz + hz);
        float n = tanhf_(inn + r * hn);
        float hv = (1.0f - z) * n + z * hl[j];
        hnext[b * 1024 + j] = hv;
        combined[((size_t)b * TT + t) * 2048 + j] = hv;
    }
}

// ---------------------------------------------------------------------------
// qw = h_next @ Wq + bq   (WqT is [N=1024][K=1024] fp32)
// ---------------------------------------------------------------------------
__global__ __launch_bounds__(256)
void qw_step(const float* __restrict__ h, const float* __restrict__ WqT,
             const float* __restrict__ bq, float* __restrict__ qw)
{
    __shared__ float hl[1024];
    __shared__ float red[256];
    const int b = blockIdx.x >> 3, jc = blockIdx.x & 7;
    const int tid = threadIdx.x, jl = tid & 127, kh = tid >> 7;
    const int j = jc * 128 + jl;
    for (int i = tid; i < 1024; i += 256) hl[i] = h[b * 1024 + i];
    __syncthreads();
    const float* w0 = WqT + (size_t)j * 1024 + kh * 512;
    const float* hk = hl + kh * 512;
    float a0 = 0;
    for (int c = 0; c < 512; c += 4) {
        float4 t0 = *(const float4*)(w0 + c);
        a0 += t0.x * hk[c] + t0.y * hk[c + 1] + t0.z * hk[c + 2] + t0.w * hk[c + 3];
    }
    red[tid] = a0;
    __syncthreads();
    if (kh == 0) qw[b * 1024 + j] = red[jl] + red[jl + 128] + bq[j];
}

// ---------------------------------------------------------------------------
// attention: scores=tanh(qw+vw)@wc+bc; softmax(+mask); ctx=w@values;
// writes combined[:,t,H:2H]. grid 32 (one WG per b), 256 thr. All fp32.
// ---------------------------------------------------------------------------
__global__ __launch_bounds__(256)
void attn_step(const float* __restrict__ qw, const float* __restrict__ vw,
               const float* __restrict__ values, const float* __restrict__ wc,
               const float* __restrict__ bc, const int* __restrict__ mask,
               float* __restrict__ combined, int t)
{
    __shared__ float qwl[1024];
    __shared__ float wcl[1024];
    __shared__ float w_lds[128];
    __shared__ float red[256];
    const int b = blockIdx.x, tid = threadIdx.x;
    for (int i = tid; i < 1024; i += 256) { qwl[i] = qw[b * 1024 + i]; wcl[i] = wc[i]; }
    __syncthreads();

    const int s = tid >> 1, kh = tid & 1;
    const float* vwp = vw + ((size_t)b * SS + s) * 1024 + kh * 512;
    const float* qq = qwl + kh * 512;
    const float* ww = wcl + kh * 512;
    float part = 0;
    for (int c = 0; c < 512; c += 4) {
        float4 t4 = *(const float4*)(vwp + c);
        part += tanhf_(qq[c] + t4.x) * ww[c];
        part += tanhf_(qq[c + 1] + t4.y) * ww[c + 1];
        part += tanhf_(qq[c + 2] + t4.z) * ww[c + 2];
        part += tanhf_(qq[c + 3] + t4.w) * ww[c + 3];
    }
    red[tid] = part;
    __syncthreads();
    if (kh == 0) {
        float sc = red[2 * s] + red[2 * s + 1] + bc[0];
        if (mask[b * SS + s] == 0) sc += -1e30f;
        w_lds[s] = sc;
    }
    __syncthreads();
    if (tid < 64) {
        float a = w_lds[tid], b2 = w_lds[tid + 64];
        float m = fmaxf(a, b2);
#pragma unroll
        for (int off = 32; off; off >>= 1) m = fmaxf(m, __shfl_xor(m, off));
        float e0 = __expf(a - m), e1 = __expf(b2 - m);
        float ssum = e0 + e1;
#pragma unroll
        for (int off = 32; off; off >>= 1) ssum += __shfl_xor(ssum, off);
        float inv = 1.0f / ssum;
        w_lds[tid] = e0 * inv; w_lds[tid + 64] = e1 * inv;
    }
    __syncthreads();

    const int j0 = tid * 4;
    float c0 = 0, c1 = 0, c2 = 0, c3 = 0;
    const float* vp = values + (size_t)b * SS * 1024 + j0;
    for (int si = 0; si < SS; ++si) {
        float wv = w_lds[si];
        float4 t4 = *(const float4*)(vp + (size_t)si * 1024);
        c0 += wv * t4.x; c1 += wv * t4.y; c2 += wv * t4.z; c3 += wv * t4.w;
    }
    size_t o = ((size_t)b * TT + t) * 2048 + 1024 + j0;
    combined[o] = c0; combined[o + 1] = c1; combined[o + 2] = c2; combined[o + 3] = c3;
}

__global__ __launch_bounds__(256)
void copy_h_final(const float* __restrict__ h, float* __restrict__ out)
{
    int i = blockIdx.x * 256 + threadIdx.x;
    out[i] = h[i];
}

// ---------------------------------------------------------------------------
extern "C" void kernel_launch(void* const* d_in, const int* in_sizes, int n_in,
                              void* d_out, int out_size, void* d_ws, size_t ws_size,
                              hipStream_t stream)
{
    const float* enc_out = (const float*)d_in[0];   // [B,S,2H]
    const float* enc_hid = (const float*)d_in[1];   // [B,2H]
    const int*   maskp   = (const int*)d_in[2];     // [B,S]
    const int*   tgt     = (const int*)d_in[3];     // [B,T]
    const float* emb     = (const float*)d_in[4];   // [V,H]
    const float* Wq      = (const float*)d_in[5];
    const float* bq      = (const float*)d_in[6];
    const float* Wv      = (const float*)d_in[7];
    const float* bv      = (const float*)d_in[8];
    const float* wc      = (const float*)d_in[9];
    const float* bc      = (const float*)d_in[10];
    const float* Wih     = (const float*)d_in[11];
    const float* bih     = (const float*)d_in[12];
    const float* Whh     = (const float*)d_in[13];
    const float* bhh     = (const float*)d_in[14];
    const float* Wproj   = (const float*)d_in[15];
    const float* bproj   = (const float*)d_in[16];
    const float* Wout    = (const float*)d_in[17];
    const float* bout    = (const float*)d_in[18];

    // Workspace layout (~113 MB, fp32)
    char* ws = (char*)d_ws;
    float* WhhT     = (float*)ws; ws += (size_t)3072 * 1024 * 4;
    float* WqT      = (float*)ws; ws += (size_t)1024 * 1024 * 4;
    float* values   = (float*)ws; ws += (size_t)4096 * 1024 * 4;  // [B*S,H]
    float* vw       = (float*)ws; ws += (size_t)4096 * 1024 * 4;  // [B*S,H]
    float* GI       = (float*)ws; ws += (size_t)3072 * 3072 * 4;  // [B*T,3H]
    float* combined = (float*)ws; ws += (size_t)3072 * 2048 * 4;  // [B*T,2H]
    float* hbuf     = (float*)ws; ws += (size_t)2 * 32 * 1024 * 4;
    float* qwb      = (float*)ws; ws += (size_t)32 * 1024 * 4;

    // Weight transposes for the per-step fp32 kernels
    transpose_f32<<<dim3(3072 / 64, 1024 / 64), 256, 0, stream>>>(Whh, WhhT, 1024, 3072);
    transpose_f32<<<dim3(1024 / 64, 1024 / 64), 256, 0, stream>>>(Wq, WqT, 1024, 1024);

    // values = enc_out @ Wproj + bproj   [4096,2048]@[2048,1024]
    gemm128<false><<<dim3(8, 32), 256, 0, stream>>>(
        enc_out, 2048, nullptr, nullptr, Wproj, 1024, bproj, values, 1024, 4096, 1024, 2048);
    // h0 = enc_hid @ Wproj + bproj
    gemm128<false><<<dim3(8, 1), 256, 0, stream>>>(
        enc_hid, 2048, nullptr, nullptr, Wproj, 1024, bproj, hbuf, 1024, 32, 1024, 2048);
    // vw = values @ Wv + bv
    gemm128<false><<<dim3(8, 32), 256, 0, stream>>>(
        values, 1024, nullptr, nullptr, Wv, 1024, bv, vw, 1024, 4096, 1024, 1024);
    // GI = emb[tgt] @ Wih + bih   [3072,1024]@[1024,3072]
    gemm128<true><<<dim3(24, 24), 256, 0, stream>>>(
        nullptr, 1024, tgt, emb, Wih, 3072, bih, GI, 3072, 3072, 3072, 1024);

    for (int t = 0; t < TT; ++t) {
        const float* hc = hbuf + (size_t)(t & 1) * 32768;
        float*       hn = hbuf + (size_t)((t + 1) & 1) * 32768;
        gru_step<<<256, 256, 0, stream>>>(hc, hn, GI, WhhT, bhh, combined, t);
        qw_step<<<256, 256, 0, stream>>>(hn, WqT, bq, qwb);
        attn_step<<<32, 256, 0, stream>>>(qwb, vw, values, wc, bc, maskp, combined, t);
    }

    // logits = combined @ Wout + bout -> fp32 straight into d_out
    gemm128<false><<<dim3(250, 24), 256, 0, stream>>>(
        combined, 2048, nullptr, nullptr, Wout, 32000, bout, (float*)d_out, 32000,
        3072, 32000, 2048);

    // h_final (after t=95, result is in hbuf[0])
    copy_h_final<<<128, 256, 0, stream>>>(hbuf, (float*)d_out + (size_t)BB * TT * VV);
}